// Round 2
// baseline (1339.179 us; speedup 1.0000x reference)
//
#include <hip/hip_runtime.h>

// ---------------------------------------------------------------------------
// WGraphSAGE: h' = relu(agg(h) @ W.T + b) x2, then out = h @ Wo.T + bo
// agg(h)[n] = deg*sum_m[n]/((deg+1)*sum_w[n]) + h[n]/(deg+1)   (0 if deg==0)
// Strategy: build CSR by dst once per launch (count/scan/scatter), then
// pull-based atomic-free aggregation (1 wave per node, float2 per lane,
// 4-edge unroll for MLP), then LDS-tiled FC kernels (j-fast transposed-W
// staging = conflict-free writes; 80KB LDS = 2 blocks/CU for the 128-out FC).
// ---------------------------------------------------------------------------

#define D 128  // feature dim (F_IN == H == 128)

__global__ void count_kernel(const int* __restrict__ dst, int* __restrict__ deg, int e) {
    int i = blockIdx.x * blockDim.x + threadIdx.x;
    if (i < e) atomicAdd(&deg[dst[i]], 1);
}

// single-block exclusive scan over deg -> rowptr[0..n], rowptr[n] = total
__global__ void scan_kernel(const int* __restrict__ deg, int* __restrict__ rowptr, int n) {
    __shared__ int part[1024];
    const int t = threadIdx.x;
    const int per = (n + 1023) / 1024;
    const int beg = t * per;
    const int end = min(n, beg + per);
    int s = 0;
    for (int i = beg; i < end; ++i) s += deg[i];
    part[t] = s;
    __syncthreads();
    for (int off = 1; off < 1024; off <<= 1) {
        int v = (t >= off) ? part[t - off] : 0;
        __syncthreads();
        part[t] += v;
        __syncthreads();
    }
    int base = part[t] - s;  // exclusive prefix for this thread's chunk
    for (int i = beg; i < end; ++i) { rowptr[i] = base; base += deg[i]; }
    if (t == 1023) rowptr[n] = part[1023];
}

__global__ void scatter_kernel(const int* __restrict__ src, const int* __restrict__ dst,
                               const float* __restrict__ w, const int* __restrict__ rowptr,
                               int* __restrict__ cur, int* __restrict__ csrc,
                               float* __restrict__ cw, int e) {
    int i = blockIdx.x * blockDim.x + threadIdx.x;
    if (i < e) {
        int d = dst[i];
        int pos = rowptr[d] + atomicAdd(&cur[d], 1);
        csrc[pos] = src[i];
        cw[pos]   = w[i];
    }
}

// one wave (64 lanes) per node; lane l owns dims 2l,2l+1 (float2)
__global__ __launch_bounds__(256) void agg_kernel(
        const float* __restrict__ h, const int* __restrict__ rowptr,
        const int* __restrict__ csrc, const float* __restrict__ cw,
        float* __restrict__ neigh, int n) {
    const int wid  = (blockIdx.x * blockDim.x + threadIdx.x) >> 6;
    const int lane = threadIdx.x & 63;
    if (wid >= n) return;
    const int beg = rowptr[wid], end = rowptr[wid + 1];
    float2 a0 = {0.f, 0.f}, a1 = {0.f, 0.f}, a2 = {0.f, 0.f}, a3 = {0.f, 0.f};
    float ws = 0.f;
    const int co = lane * 2;
    int e = beg;
    if ((e & 1) && e < end) {  // peel to even index -> int2/float2 loads aligned
        int s0 = csrc[e]; float w0 = cw[e];
        float2 v0 = *(const float2*)(h + (size_t)s0 * D + co);
        a0.x = fmaf(v0.x, w0, a0.x); a0.y = fmaf(v0.y, w0, a0.y);
        ws += w0; ++e;
    }
    for (; e + 3 < end; e += 4) {  // 4 independent gather chains
        int2   s01 = *(const int2*)(csrc + e), s23 = *(const int2*)(csrc + e + 2);
        float2 w01 = *(const float2*)(cw + e), w23 = *(const float2*)(cw + e + 2);
        float2 v0 = *(const float2*)(h + (size_t)s01.x * D + co);
        float2 v1 = *(const float2*)(h + (size_t)s01.y * D + co);
        float2 v2 = *(const float2*)(h + (size_t)s23.x * D + co);
        float2 v3 = *(const float2*)(h + (size_t)s23.y * D + co);
        a0.x = fmaf(v0.x, w01.x, a0.x); a0.y = fmaf(v0.y, w01.x, a0.y);
        a1.x = fmaf(v1.x, w01.y, a1.x); a1.y = fmaf(v1.y, w01.y, a1.y);
        a2.x = fmaf(v2.x, w23.x, a2.x); a2.y = fmaf(v2.y, w23.x, a2.y);
        a3.x = fmaf(v3.x, w23.y, a3.x); a3.y = fmaf(v3.y, w23.y, a3.y);
        ws += (w01.x + w01.y) + (w23.x + w23.y);
    }
    for (; e < end; ++e) {
        int s0 = csrc[e]; float w0 = cw[e];
        float2 v0 = *(const float2*)(h + (size_t)s0 * D + co);
        a0.x = fmaf(v0.x, w0, a0.x); a0.y = fmaf(v0.y, w0, a0.y);
        ws += w0;
    }
    a0.x += a1.x + a2.x + a3.x;
    a0.y += a1.y + a2.y + a3.y;
    float2 o = {0.f, 0.f};
    if (end > beg) {
        const float deg  = (float)(end - beg);
        const float sw   = (ws == 0.f) ? 1.f : ws;
        const float invm = deg / ((deg + 1.f) * sw);
        const float invd = 1.f / (deg + 1.f);
        float2 hc = *(const float2*)(h + (size_t)wid * D + co);
        o.x = fmaf(a0.x, invm, hc.x * invd);
        o.y = fmaf(a0.y, invm, hc.y * invd);
    }
    *(float2*)(neigh + (size_t)wid * D + co) = o;
}

// Y[n][j] = (relu)( sum_k X[n][k] * W[j][k] + B[j] ), K = 128
// LDS: sWt[k][j] transposed-W; j-fast staging -> bank = j%32, conflict-free
// writes, no padding needed (reads are within-row / broadcast, pad-invariant).
// fc<128,4>: 64KB + 16KB = 80KB -> 2 blocks/CU. TM nodes x 4 outs per thread.
template <int OUT, int TM, bool RELU>
__global__ __launch_bounds__(256) void fc_kernel(
        const float* __restrict__ X, const float* __restrict__ W,
        const float* __restrict__ B, float* __restrict__ Y, int n) {
    constexpr int TNX = OUT / 4;    // threads along output dim
    constexpr int TY  = 256 / TNX;  // thread rows
    constexpr int NT  = TY * TM;    // node tile
    __shared__ float sWt[D][OUT];
    __shared__ float sN[NT][D];
    const int t = threadIdx.x;
    // stage W transposed, j-fast: lane writes column j=t%OUT -> bank j%32
    for (int p = t; p < OUT * (D / 4); p += 256) {
        int j = p % OUT, k4 = (p / OUT) << 2;
        const float4 v = *(const float4*)(W + j * D + k4);
        sWt[k4 + 0][j] = v.x; sWt[k4 + 1][j] = v.y;
        sWt[k4 + 2][j] = v.z; sWt[k4 + 3][j] = v.w;
    }
    const int tx = t % TNX, ty = t / TNX;
    const float4 bv = *(const float4*)(B + tx * 4);
    const int ntiles = (n + NT - 1) / NT;
    for (int tile = blockIdx.x; tile < ntiles; tile += gridDim.x) {
        const int node0 = tile * NT;
        __syncthreads();  // W ready (first iter) / prev compute done (later)
        for (int p = t; p < NT * (D / 4); p += 256) {
            int r = p >> 5, c = (p & 31) << 2;
            int nd = node0 + r;
            float4 v = make_float4(0.f, 0.f, 0.f, 0.f);
            if (nd < n) v = *(const float4*)(X + (size_t)nd * D + c);
            *(float4*)&sN[r][c] = v;
        }
        __syncthreads();
        float acc[TM][4];
        #pragma unroll
        for (int m = 0; m < TM; ++m)
            acc[m][0] = acc[m][1] = acc[m][2] = acc[m][3] = 0.f;
        for (int k = 0; k < D; k += 4) {
            float4 xv[TM];
            #pragma unroll
            for (int m = 0; m < TM; ++m) xv[m] = *(const float4*)&sN[ty * TM + m][k];
            #pragma unroll
            for (int i = 0; i < 4; ++i) {
                const float4 wv = *(const float4*)&sWt[k + i][tx * 4];
                #pragma unroll
                for (int m = 0; m < TM; ++m) {
                    const float x = (i == 0) ? xv[m].x : (i == 1) ? xv[m].y
                                  : (i == 2) ? xv[m].z : xv[m].w;
                    acc[m][0] = fmaf(x, wv.x, acc[m][0]);
                    acc[m][1] = fmaf(x, wv.y, acc[m][1]);
                    acc[m][2] = fmaf(x, wv.z, acc[m][2]);
                    acc[m][3] = fmaf(x, wv.w, acc[m][3]);
                }
            }
        }
        #pragma unroll
        for (int m = 0; m < TM; ++m) {
            const int nd = node0 + ty * TM + m;
            if (nd < n) {
                float4 o;
                o.x = acc[m][0] + bv.x; o.y = acc[m][1] + bv.y;
                o.z = acc[m][2] + bv.z; o.w = acc[m][3] + bv.w;
                if (RELU) {
                    o.x = fmaxf(o.x, 0.f); o.y = fmaxf(o.y, 0.f);
                    o.z = fmaxf(o.z, 0.f); o.w = fmaxf(o.w, 0.f);
                }
                *(float4*)(Y + (size_t)nd * OUT + tx * 4) = o;
            }
        }
    }
}

extern "C" void kernel_launch(void* const* d_in, const int* in_sizes, int n_in,
                              void* d_out, int out_size, void* d_ws, size_t ws_size,
                              hipStream_t stream) {
    const float* feat = (const float*)d_in[0];
    const int*   src  = (const int*)d_in[1];
    const int*   dst  = (const int*)d_in[2];
    const float* w    = (const float*)d_in[3];
    const float* W1   = (const float*)d_in[4];
    const float* b1   = (const float*)d_in[5];
    const float* W2   = (const float*)d_in[6];
    const float* b2   = (const float*)d_in[7];
    const float* Wo   = (const float*)d_in[8];
    const float* bo   = (const float*)d_in[9];
    float* out = (float*)d_out;

    const int n = in_sizes[0] / D;   // 40000
    const int e = in_sizes[1];       // 640000

    // workspace carve-out (256B aligned slices)
    char* ws = (char*)d_ws;
    size_t off = 0;
    auto carve = [&](size_t bytes) {
        char* p = ws + off;
        off = (off + bytes + 255) & ~(size_t)255;
        return p;
    };
    int*   deg    = (int*)carve((size_t)n * 4);
    int*   cur    = (int*)carve((size_t)n * 4);
    int*   rowptr = (int*)carve((size_t)(n + 1) * 4);
    int*   csrc   = (int*)carve((size_t)e * 4);
    float* cw     = (float*)carve((size_t)e * 4);
    float* neigh  = (float*)carve((size_t)n * D * 4);
    float* hbuf   = (float*)carve((size_t)n * D * 4);

    const int TB = 256;
    // --- CSR build (per launch; ws is re-poisoned by the harness) ---
    hipMemsetAsync(deg, 0, (size_t)n * 4, stream);
    hipMemsetAsync(cur, 0, (size_t)n * 4, stream);
    count_kernel<<<(e + TB - 1) / TB, TB, 0, stream>>>(dst, deg, e);
    scan_kernel<<<1, 1024, 0, stream>>>(deg, rowptr, n);
    scatter_kernel<<<(e + TB - 1) / TB, TB, 0, stream>>>(src, dst, w, rowptr, cur, csrc, cw, e);

    const int aggBlocks = (n + 3) / 4;  // 4 nodes (waves) per 256-thread block
    const int fc128Grid = 512;          // 2 resident blocks/CU, grid-stride tiles
    const int fc32Grid  = (n + 63) / 64;

    // --- layer 1 ---
    agg_kernel<<<aggBlocks, TB, 0, stream>>>(feat, rowptr, csrc, cw, neigh, n);
    fc_kernel<128, 4, true><<<fc128Grid, TB, 0, stream>>>(neigh, W1, b1, hbuf, n);
    // --- layer 2 ---
    agg_kernel<<<aggBlocks, TB, 0, stream>>>(hbuf, rowptr, csrc, cw, neigh, n);
    fc_kernel<128, 4, true><<<fc128Grid, TB, 0, stream>>>(neigh, W2, b2, hbuf, n);
    // --- classifier ---
    fc_kernel<32, 2, false><<<fc32Grid, TB, 0, stream>>>(hbuf, Wo, bo, out, n);
}

// Round 3
// 373.530 us; speedup vs baseline: 3.5852x; 3.5852x over previous
//
#include <hip/hip_runtime.h>

// ---------------------------------------------------------------------------
// WGraphSAGE: h' = relu(agg(h) @ W.T + b) x2, then out = h @ Wo.T + bo
// agg(h)[n] = deg*sum_m[n]/((deg+1)*sum_w[n]) + h[n]/(deg+1)   (0 if deg==0)
// R2 fix: fc_kernel spilled (VGPR=256, 740MB scratch FETCH, 513us/dispatch).
// Cause: full unroll of the constant-trip k-loop hoisted ds_read batches.
// Fix: #pragma unroll 2 bounds the live-load window (~90 VGPR).
// ---------------------------------------------------------------------------

#define D 128  // feature dim (F_IN == H == 128)

__global__ void count_kernel(const int* __restrict__ dst, int* __restrict__ deg, int e) {
    int i = blockIdx.x * blockDim.x + threadIdx.x;
    if (i < e) atomicAdd(&deg[dst[i]], 1);
}

// single-block exclusive scan over deg -> rowptr[0..n], rowptr[n] = total
__global__ void scan_kernel(const int* __restrict__ deg, int* __restrict__ rowptr, int n) {
    __shared__ int part[1024];
    const int t = threadIdx.x;
    const int per = (n + 1023) / 1024;
    const int beg = t * per;
    const int end = min(n, beg + per);
    int s = 0;
    for (int i = beg; i < end; ++i) s += deg[i];
    part[t] = s;
    __syncthreads();
    for (int off = 1; off < 1024; off <<= 1) {
        int v = (t >= off) ? part[t - off] : 0;
        __syncthreads();
        part[t] += v;
        __syncthreads();
    }
    int base = part[t] - s;  // exclusive prefix for this thread's chunk
    for (int i = beg; i < end; ++i) { rowptr[i] = base; base += deg[i]; }
    if (t == 1023) rowptr[n] = part[1023];
}

__global__ void scatter_kernel(const int* __restrict__ src, const int* __restrict__ dst,
                               const float* __restrict__ w, const int* __restrict__ rowptr,
                               int* __restrict__ cur, int* __restrict__ csrc,
                               float* __restrict__ cw, int e) {
    int i = blockIdx.x * blockDim.x + threadIdx.x;
    if (i < e) {
        int d = dst[i];
        int pos = rowptr[d] + atomicAdd(&cur[d], 1);
        csrc[pos] = src[i];
        cw[pos]   = w[i];
    }
}

// one wave (64 lanes) per node; lane l owns dims 2l,2l+1 (float2)
__global__ __launch_bounds__(256) void agg_kernel(
        const float* __restrict__ h, const int* __restrict__ rowptr,
        const int* __restrict__ csrc, const float* __restrict__ cw,
        float* __restrict__ neigh, int n) {
    const int wid  = (blockIdx.x * blockDim.x + threadIdx.x) >> 6;
    const int lane = threadIdx.x & 63;
    if (wid >= n) return;
    const int beg = rowptr[wid], end = rowptr[wid + 1];
    float2 a0 = {0.f, 0.f}, a1 = {0.f, 0.f}, a2 = {0.f, 0.f}, a3 = {0.f, 0.f};
    float ws = 0.f;
    const int co = lane * 2;
    int e = beg;
    if ((e & 1) && e < end) {  // peel to even index -> int2/float2 loads aligned
        int s0 = csrc[e]; float w0 = cw[e];
        float2 v0 = *(const float2*)(h + (size_t)s0 * D + co);
        a0.x = fmaf(v0.x, w0, a0.x); a0.y = fmaf(v0.y, w0, a0.y);
        ws += w0; ++e;
    }
    for (; e + 3 < end; e += 4) {  // 4 independent gather chains
        int2   s01 = *(const int2*)(csrc + e), s23 = *(const int2*)(csrc + e + 2);
        float2 w01 = *(const float2*)(cw + e), w23 = *(const float2*)(cw + e + 2);
        float2 v0 = *(const float2*)(h + (size_t)s01.x * D + co);
        float2 v1 = *(const float2*)(h + (size_t)s01.y * D + co);
        float2 v2 = *(const float2*)(h + (size_t)s23.x * D + co);
        float2 v3 = *(const float2*)(h + (size_t)s23.y * D + co);
        a0.x = fmaf(v0.x, w01.x, a0.x); a0.y = fmaf(v0.y, w01.x, a0.y);
        a1.x = fmaf(v1.x, w01.y, a1.x); a1.y = fmaf(v1.y, w01.y, a1.y);
        a2.x = fmaf(v2.x, w23.x, a2.x); a2.y = fmaf(v2.y, w23.x, a2.y);
        a3.x = fmaf(v3.x, w23.y, a3.x); a3.y = fmaf(v3.y, w23.y, a3.y);
        ws += (w01.x + w01.y) + (w23.x + w23.y);
    }
    for (; e < end; ++e) {
        int s0 = csrc[e]; float w0 = cw[e];
        float2 v0 = *(const float2*)(h + (size_t)s0 * D + co);
        a0.x = fmaf(v0.x, w0, a0.x); a0.y = fmaf(v0.y, w0, a0.y);
        ws += w0;
    }
    a0.x += a1.x + a2.x + a3.x;
    a0.y += a1.y + a2.y + a3.y;
    float2 o = {0.f, 0.f};
    if (end > beg) {
        const float deg  = (float)(end - beg);
        const float sw   = (ws == 0.f) ? 1.f : ws;
        const float invm = deg / ((deg + 1.f) * sw);
        const float invd = 1.f / (deg + 1.f);
        float2 hc = *(const float2*)(h + (size_t)wid * D + co);
        o.x = fmaf(a0.x, invm, hc.x * invd);
        o.y = fmaf(a0.y, invm, hc.y * invd);
    }
    *(float2*)(neigh + (size_t)wid * D + co) = o;
}

// Y[n][j] = (relu)( sum_k X[n][k] * W[j][k] + B[j] ), K = 128
// LDS: sWt[k][j] transposed-W; j-fast staging -> bank = j%32, conflict-free
// writes, no padding needed (reads are within-row / broadcast, pad-invariant).
// fc<128,4>: 64KB + 16KB = 80KB -> 2 blocks/CU. TM nodes x 4 outs per thread.
// k-loop: #pragma unroll 2 — full unroll spilled (R2: VGPR=256, 740MB scratch).
template <int OUT, int TM, bool RELU>
__global__ __launch_bounds__(256) void fc_kernel(
        const float* __restrict__ X, const float* __restrict__ W,
        const float* __restrict__ B, float* __restrict__ Y, int n) {
    constexpr int TNX = OUT / 4;    // threads along output dim
    constexpr int TY  = 256 / TNX;  // thread rows
    constexpr int NT  = TY * TM;    // node tile
    __shared__ float sWt[D][OUT];
    __shared__ float sN[NT][D];
    const int t = threadIdx.x;
    // stage W transposed, j-fast: lane writes column j=t%OUT -> bank j%32
    for (int p = t; p < OUT * (D / 4); p += 256) {
        int j = p % OUT, k4 = (p / OUT) << 2;
        const float4 v = *(const float4*)(W + j * D + k4);
        sWt[k4 + 0][j] = v.x; sWt[k4 + 1][j] = v.y;
        sWt[k4 + 2][j] = v.z; sWt[k4 + 3][j] = v.w;
    }
    const int tx = t % TNX, ty = t / TNX;
    const float4 bv = *(const float4*)(B + tx * 4);
    const int ntiles = (n + NT - 1) / NT;
    for (int tile = blockIdx.x; tile < ntiles; tile += gridDim.x) {
        const int node0 = tile * NT;
        __syncthreads();  // W ready (first iter) / prev compute done (later)
        for (int p = t; p < NT * (D / 4); p += 256) {
            int r = p >> 5, c = (p & 31) << 2;
            int nd = node0 + r;
            float4 v = make_float4(0.f, 0.f, 0.f, 0.f);
            if (nd < n) v = *(const float4*)(X + (size_t)nd * D + c);
            *(float4*)&sN[r][c] = v;
        }
        __syncthreads();
        float acc[TM][4];
        #pragma unroll
        for (int m = 0; m < TM; ++m)
            acc[m][0] = acc[m][1] = acc[m][2] = acc[m][3] = 0.f;
        #pragma unroll 2
        for (int k = 0; k < D; k += 4) {
            float4 xv[TM];
            #pragma unroll
            for (int m = 0; m < TM; ++m) xv[m] = *(const float4*)&sN[ty * TM + m][k];
            #pragma unroll
            for (int i = 0; i < 4; ++i) {
                const float4 wv = *(const float4*)&sWt[k + i][tx * 4];
                #pragma unroll
                for (int m = 0; m < TM; ++m) {
                    const float x = (i == 0) ? xv[m].x : (i == 1) ? xv[m].y
                                  : (i == 2) ? xv[m].z : xv[m].w;
                    acc[m][0] = fmaf(x, wv.x, acc[m][0]);
                    acc[m][1] = fmaf(x, wv.y, acc[m][1]);
                    acc[m][2] = fmaf(x, wv.z, acc[m][2]);
                    acc[m][3] = fmaf(x, wv.w, acc[m][3]);
                }
            }
        }
        #pragma unroll
        for (int m = 0; m < TM; ++m) {
            const int nd = node0 + ty * TM + m;
            if (nd < n) {
                float4 o;
                o.x = acc[m][0] + bv.x; o.y = acc[m][1] + bv.y;
                o.z = acc[m][2] + bv.z; o.w = acc[m][3] + bv.w;
                if (RELU) {
                    o.x = fmaxf(o.x, 0.f); o.y = fmaxf(o.y, 0.f);
                    o.z = fmaxf(o.z, 0.f); o.w = fmaxf(o.w, 0.f);
                }
                *(float4*)(Y + (size_t)nd * OUT + tx * 4) = o;
            }
        }
    }
}

extern "C" void kernel_launch(void* const* d_in, const int* in_sizes, int n_in,
                              void* d_out, int out_size, void* d_ws, size_t ws_size,
                              hipStream_t stream) {
    const float* feat = (const float*)d_in[0];
    const int*   src  = (const int*)d_in[1];
    const int*   dst  = (const int*)d_in[2];
    const float* w    = (const float*)d_in[3];
    const float* W1   = (const float*)d_in[4];
    const float* b1   = (const float*)d_in[5];
    const float* W2   = (const float*)d_in[6];
    const float* b2   = (const float*)d_in[7];
    const float* Wo   = (const float*)d_in[8];
    const float* bo   = (const float*)d_in[9];
    float* out = (float*)d_out;

    const int n = in_sizes[0] / D;   // 40000
    const int e = in_sizes[1];       // 640000

    // workspace carve-out (256B aligned slices)
    char* ws = (char*)d_ws;
    size_t off = 0;
    auto carve = [&](size_t bytes) {
        char* p = ws + off;
        off = (off + bytes + 255) & ~(size_t)255;
        return p;
    };
    int*   deg    = (int*)carve((size_t)n * 4);
    int*   cur    = (int*)carve((size_t)n * 4);
    int*   rowptr = (int*)carve((size_t)(n + 1) * 4);
    int*   csrc   = (int*)carve((size_t)e * 4);
    float* cw     = (float*)carve((size_t)e * 4);
    float* neigh  = (float*)carve((size_t)n * D * 4);
    float* hbuf   = (float*)carve((size_t)n * D * 4);

    const int TB = 256;
    // --- CSR build (per launch; ws is re-poisoned by the harness) ---
    // one memset spans deg..cur (adjacent carves; pad bytes don't matter)
    hipMemsetAsync(deg, 0, (size_t)((char*)(cur + n) - (char*)deg), stream);
    count_kernel<<<(e + TB - 1) / TB, TB, 0, stream>>>(dst, deg, e);
    scan_kernel<<<1, 1024, 0, stream>>>(deg, rowptr, n);
    scatter_kernel<<<(e + TB - 1) / TB, TB, 0, stream>>>(src, dst, w, rowptr, cur, csrc, cw, e);

    const int aggBlocks = (n + 3) / 4;  // 4 nodes (waves) per 256-thread block
    const int fc128Grid = 512;          // 2 resident blocks/CU, grid-stride tiles
    const int fc32Grid  = (n + 63) / 64;

    // --- layer 1 ---
    agg_kernel<<<aggBlocks, TB, 0, stream>>>(feat, rowptr, csrc, cw, neigh, n);
    fc_kernel<128, 4, true><<<fc128Grid, TB, 0, stream>>>(neigh, W1, b1, hbuf, n);
    // --- layer 2 ---
    agg_kernel<<<aggBlocks, TB, 0, stream>>>(hbuf, rowptr, csrc, cw, neigh, n);
    fc_kernel<128, 4, true><<<fc128Grid, TB, 0, stream>>>(neigh, W2, b2, hbuf, n);
    // --- classifier ---
    fc_kernel<32, 2, false><<<fc32Grid, TB, 0, stream>>>(hbuf, Wo, bo, out, n);
}

// Round 7
// 315.082 us; speedup vs baseline: 4.2503x; 1.1855x over previous
//
#include <hip/hip_runtime.h>

// ---------------------------------------------------------------------------
// WGraphSAGE: h' = relu(agg(h) @ W.T + b) x2, then out = h @ Wo.T + bo
// agg(h)[n] = deg*sum_m[n]/((deg+1)*sum_w[n]) + h[n]/(deg+1)   (0 if deg==0)
// R2->R3: fc spill fix (unroll 2): 1339 -> 373.5 us.
// R3 finding: single-block scan = 64 us -> R4: 3-phase hierarchical scan.
// R4/R5/R6 timed out (no data) -> resubmitting unchanged for measurement.
// Pending: hierarchical scan + half-wave float4 agg (lanes 0-31 even-slot
// edge, lanes 32-63 odd-slot edge, 4 dims/lane -> 2 edges/gather instr,
// 1.5 VMEM instr/edge (was 2), shfl_xor(32) combine).
// ---------------------------------------------------------------------------

#define D 128  // feature dim (F_IN == H == 128)

__global__ void count_kernel(const int* __restrict__ dst, int* __restrict__ deg, int e) {
    int i = blockIdx.x * blockDim.x + threadIdx.x;
    if (i < e) atomicAdd(&deg[dst[i]], 1);
}

// --- hierarchical exclusive scan: deg[0..n) -> rowptr[0..n] ---
// phase 1: per-block (1024 elems) tree reduction -> bsum[b]
__global__ void scan_blocksum(const int* __restrict__ deg, int* __restrict__ bsum, int n) {
    __shared__ int red[1024];
    const int t = threadIdx.x;
    const int i = blockIdx.x * 1024 + t;
    red[t] = (i < n) ? deg[i] : 0;
    __syncthreads();
    for (int off = 512; off > 0; off >>= 1) {
        if (t < off) red[t] += red[t + off];
        __syncthreads();
    }
    if (t == 0) bsum[blockIdx.x] = red[0];
}

// phase 2: one wave scans nb (<=64) block sums -> exclusive bbase[b]
__global__ void scan_bsum(const int* __restrict__ bsum, int* __restrict__ bbase, int nb) {
    const int l = threadIdx.x;
    int s = (l < nb) ? bsum[l] : 0;
    int v = s;
    for (int off = 1; off < 64; off <<= 1) {
        int u = __shfl_up(v, off, 64);
        if (l >= off) v += u;
    }
    if (l < nb) bbase[l] = v - s;  // exclusive prefix
}

// phase 3: per-block Hillis-Steele scan + bbase -> rowptr (+rowptr[n])
__global__ void scan_write(const int* __restrict__ deg, const int* __restrict__ bbase,
                           int* __restrict__ rowptr, int n) {
    __shared__ int part[1024];
    const int t = threadIdx.x;
    const int i = blockIdx.x * 1024 + t;
    const int v = (i < n) ? deg[i] : 0;
    part[t] = v;
    __syncthreads();
    for (int off = 1; off < 1024; off <<= 1) {
        int u = (t >= off) ? part[t - off] : 0;
        __syncthreads();
        part[t] += u;
        __syncthreads();
    }
    const int incl = part[t];
    const int base = bbase[blockIdx.x];
    if (i < n) rowptr[i] = base + incl - v;  // exclusive
    if (i == n - 1) rowptr[n] = base + incl;
}

__global__ void scatter_kernel(const int* __restrict__ src, const int* __restrict__ dst,
                               const float* __restrict__ w, const int* __restrict__ rowptr,
                               int* __restrict__ cur, int* __restrict__ csrc,
                               float* __restrict__ cw, int e) {
    int i = blockIdx.x * blockDim.x + threadIdx.x;
    if (i < e) {
        int d = dst[i];
        int pos = rowptr[d] + atomicAdd(&cur[d], 1);
        csrc[pos] = src[i];
        cw[pos]   = w[i];
    }
}

// one wave per node; half-wave float4: lane l -> half=l>>5, q=l&31 owns dims
// 4q..4q+3 of edges with slot parity == half. 2 edges per gather instruction.
__global__ __launch_bounds__(256) void agg_kernel(
        const float* __restrict__ h, const int* __restrict__ rowptr,
        const int* __restrict__ csrc, const float* __restrict__ cw,
        float* __restrict__ neigh, int n) {
    const int wid  = (blockIdx.x * blockDim.x + threadIdx.x) >> 6;
    const int lane = threadIdx.x & 63;
    if (wid >= n) return;
    const int half = lane >> 5;
    const int q4   = (lane & 31) << 2;
    const int beg = rowptr[wid], end = rowptr[wid + 1];
    float4 aA = {0.f, 0.f, 0.f, 0.f}, aB = {0.f, 0.f, 0.f, 0.f};
    float ws = 0.f;
    int e = beg;
    // solo edge (peel to even index so int2/float2 meta loads are aligned):
    // all lanes gather the same row (dedup'd in cache); half 1 weights = 0.
    if ((e & 1) && e < end) {
        int s0 = csrc[e]; float w0 = half ? 0.f : cw[e];
        const float4 v = *(const float4*)(h + (size_t)s0 * D + q4);
        aA.x = fmaf(v.x, w0, aA.x); aA.y = fmaf(v.y, w0, aA.y);
        aA.z = fmaf(v.z, w0, aA.z); aA.w = fmaf(v.w, w0, aA.w);
        ws += w0; ++e;
    }
    for (; e + 3 < end; e += 4) {  // 4 edges = 2 independent pair-gathers
        int2   sA = *(const int2*)(csrc + e), sB = *(const int2*)(csrc + e + 2);
        float2 wA = *(const float2*)(cw + e), wB = *(const float2*)(cw + e + 2);
        const int   iA = half ? sA.y : sA.x,  iB = half ? sB.y : sB.x;
        const float fA = half ? wA.y : wA.x,  fB = half ? wB.y : wB.x;
        const float4 vA = *(const float4*)(h + (size_t)iA * D + q4);
        const float4 vB = *(const float4*)(h + (size_t)iB * D + q4);
        aA.x = fmaf(vA.x, fA, aA.x); aA.y = fmaf(vA.y, fA, aA.y);
        aA.z = fmaf(vA.z, fA, aA.z); aA.w = fmaf(vA.w, fA, aA.w);
        aB.x = fmaf(vB.x, fB, aB.x); aB.y = fmaf(vB.y, fB, aB.y);
        aB.z = fmaf(vB.z, fB, aB.z); aB.w = fmaf(vB.w, fB, aB.w);
        ws += fA + fB;
    }
    if (e + 1 < end) {  // one remaining pair
        int2   sA = *(const int2*)(csrc + e);
        float2 wA = *(const float2*)(cw + e);
        const int   iA = half ? sA.y : sA.x;
        const float fA = half ? wA.y : wA.x;
        const float4 vA = *(const float4*)(h + (size_t)iA * D + q4);
        aA.x = fmaf(vA.x, fA, aA.x); aA.y = fmaf(vA.y, fA, aA.y);
        aA.z = fmaf(vA.z, fA, aA.z); aA.w = fmaf(vA.w, fA, aA.w);
        ws += fA; e += 2;
    }
    if (e < end) {  // solo tail
        int s0 = csrc[e]; float w0 = half ? 0.f : cw[e];
        const float4 v = *(const float4*)(h + (size_t)s0 * D + q4);
        aA.x = fmaf(v.x, w0, aA.x); aA.y = fmaf(v.y, w0, aA.y);
        aA.z = fmaf(v.z, w0, aA.z); aA.w = fmaf(v.w, w0, aA.w);
        ws += w0;
    }
    aA.x += aB.x; aA.y += aB.y; aA.z += aB.z; aA.w += aB.w;
    // cross-half combine: both halves hold same dims, different edge parity
    aA.x += __shfl_xor(aA.x, 32); aA.y += __shfl_xor(aA.y, 32);
    aA.z += __shfl_xor(aA.z, 32); aA.w += __shfl_xor(aA.w, 32);
    ws   += __shfl_xor(ws, 32);
    if (!half) {  // lanes 0-31 write the 512B row
        float4 o = {0.f, 0.f, 0.f, 0.f};
        if (end > beg) {
            const float deg  = (float)(end - beg);
            const float sw   = (ws == 0.f) ? 1.f : ws;
            const float invm = deg / ((deg + 1.f) * sw);
            const float invd = 1.f / (deg + 1.f);
            const float4 hc = *(const float4*)(h + (size_t)wid * D + q4);
            o.x = fmaf(aA.x, invm, hc.x * invd);
            o.y = fmaf(aA.y, invm, hc.y * invd);
            o.z = fmaf(aA.z, invm, hc.z * invd);
            o.w = fmaf(aA.w, invm, hc.w * invd);
        }
        *(float4*)(neigh + (size_t)wid * D + q4) = o;
    }
}

// Y[n][j] = (relu)( sum_k X[n][k] * W[j][k] + B[j] ), K = 128
// LDS: sWt[k][j] transposed-W; j-fast staging -> bank = j%32, conflict-free
// writes, no padding needed (reads are within-row / broadcast, pad-invariant).
// fc<128,4>: 64KB + 16KB = 80KB -> 2 blocks/CU. TM nodes x 4 outs per thread.
// k-loop: #pragma unroll 2 — full unroll spilled (R2: VGPR=256, 740MB scratch).
template <int OUT, int TM, bool RELU>
__global__ __launch_bounds__(256) void fc_kernel(
        const float* __restrict__ X, const float* __restrict__ W,
        const float* __restrict__ B, float* __restrict__ Y, int n) {
    constexpr int TNX = OUT / 4;    // threads along output dim
    constexpr int TY  = 256 / TNX;  // thread rows
    constexpr int NT  = TY * TM;    // node tile
    __shared__ float sWt[D][OUT];
    __shared__ float sN[NT][D];
    const int t = threadIdx.x;
    // stage W transposed, j-fast: lane writes column j=t%OUT -> bank j%32
    for (int p = t; p < OUT * (D / 4); p += 256) {
        int j = p % OUT, k4 = (p / OUT) << 2;
        const float4 v = *(const float4*)(W + j * D + k4);
        sWt[k4 + 0][j] = v.x; sWt[k4 + 1][j] = v.y;
        sWt[k4 + 2][j] = v.z; sWt[k4 + 3][j] = v.w;
    }
    const int tx = t % TNX, ty = t / TNX;
    const float4 bv = *(const float4*)(B + tx * 4);
    const int ntiles = (n + NT - 1) / NT;
    for (int tile = blockIdx.x; tile < ntiles; tile += gridDim.x) {
        const int node0 = tile * NT;
        __syncthreads();  // W ready (first iter) / prev compute done (later)
        for (int p = t; p < NT * (D / 4); p += 256) {
            int r = p >> 5, c = (p & 31) << 2;
            int nd = node0 + r;
            float4 v = make_float4(0.f, 0.f, 0.f, 0.f);
            if (nd < n) v = *(const float4*)(X + (size_t)nd * D + c);
            *(float4*)&sN[r][c] = v;
        }
        __syncthreads();
        float acc[TM][4];
        #pragma unroll
        for (int m = 0; m < TM; ++m)
            acc[m][0] = acc[m][1] = acc[m][2] = acc[m][3] = 0.f;
        #pragma unroll 2
        for (int k = 0; k < D; k += 4) {
            float4 xv[TM];
            #pragma unroll
            for (int m = 0; m < TM; ++m) xv[m] = *(const float4*)&sN[ty * TM + m][k];
            #pragma unroll
            for (int i = 0; i < 4; ++i) {
                const float4 wv = *(const float4*)&sWt[k + i][tx * 4];
                #pragma unroll
                for (int m = 0; m < TM; ++m) {
                    const float x = (i == 0) ? xv[m].x : (i == 1) ? xv[m].y
                                  : (i == 2) ? xv[m].z : xv[m].w;
                    acc[m][0] = fmaf(x, wv.x, acc[m][0]);
                    acc[m][1] = fmaf(x, wv.y, acc[m][1]);
                    acc[m][2] = fmaf(x, wv.z, acc[m][2]);
                    acc[m][3] = fmaf(x, wv.w, acc[m][3]);
                }
            }
        }
        #pragma unroll
        for (int m = 0; m < TM; ++m) {
            const int nd = node0 + ty * TM + m;
            if (nd < n) {
                float4 o;
                o.x = acc[m][0] + bv.x; o.y = acc[m][1] + bv.y;
                o.z = acc[m][2] + bv.z; o.w = acc[m][3] + bv.w;
                if (RELU) {
                    o.x = fmaxf(o.x, 0.f); o.y = fmaxf(o.y, 0.f);
                    o.z = fmaxf(o.z, 0.f); o.w = fmaxf(o.w, 0.f);
                }
                *(float4*)(Y + (size_t)nd * OUT + tx * 4) = o;
            }
        }
    }
}

extern "C" void kernel_launch(void* const* d_in, const int* in_sizes, int n_in,
                              void* d_out, int out_size, void* d_ws, size_t ws_size,
                              hipStream_t stream) {
    const float* feat = (const float*)d_in[0];
    const int*   src  = (const int*)d_in[1];
    const int*   dst  = (const int*)d_in[2];
    const float* w    = (const float*)d_in[3];
    const float* W1   = (const float*)d_in[4];
    const float* b1   = (const float*)d_in[5];
    const float* W2   = (const float*)d_in[6];
    const float* b2   = (const float*)d_in[7];
    const float* Wo   = (const float*)d_in[8];
    const float* bo   = (const float*)d_in[9];
    float* out = (float*)d_out;

    const int n = in_sizes[0] / D;   // 40000
    const int e = in_sizes[1];       // 640000

    // workspace carve-out (256B aligned slices)
    char* ws = (char*)d_ws;
    size_t off = 0;
    auto carve = [&](size_t bytes) {
        char* p = ws + off;
        off = (off + bytes + 255) & ~(size_t)255;
        return p;
    };
    int*   deg    = (int*)carve((size_t)n * 4);
    int*   cur    = (int*)carve((size_t)n * 4);
    int*   rowptr = (int*)carve((size_t)(n + 1) * 4);
    int*   csrc   = (int*)carve((size_t)e * 4);
    float* cw     = (float*)carve((size_t)e * 4);
    float* neigh  = (float*)carve((size_t)n * D * 4);
    float* hbuf   = (float*)carve((size_t)n * D * 4);
    const int nScanBlk = (n + 1023) / 1024;          // 40
    int* bsum  = (int*)carve((size_t)nScanBlk * 4);
    int* bbase = (int*)carve((size_t)nScanBlk * 4);

    const int TB = 256;
    // --- CSR build (per launch; ws is re-poisoned by the harness) ---
    // one memset spans deg..cur (adjacent carves; pad bytes don't matter)
    hipMemsetAsync(deg, 0, (size_t)((char*)(cur + n) - (char*)deg), stream);
    count_kernel<<<(e + TB - 1) / TB, TB, 0, stream>>>(dst, deg, e);
    scan_blocksum<<<nScanBlk, 1024, 0, stream>>>(deg, bsum, n);
    scan_bsum<<<1, 64, 0, stream>>>(bsum, bbase, nScanBlk);
    scan_write<<<nScanBlk, 1024, 0, stream>>>(deg, bbase, rowptr, n);
    scatter_kernel<<<(e + TB - 1) / TB, TB, 0, stream>>>(src, dst, w, rowptr, cur, csrc, cw, e);

    const int aggBlocks = (n + 3) / 4;  // 4 nodes (waves) per 256-thread block
    const int fc128Grid = 512;          // 2 resident blocks/CU, grid-stride tiles
    const int fc32Grid  = (n + 63) / 64;

    // --- layer 1 ---
    agg_kernel<<<aggBlocks, TB, 0, stream>>>(feat, rowptr, csrc, cw, neigh, n);
    fc_kernel<128, 4, true><<<fc128Grid, TB, 0, stream>>>(neigh, W1, b1, hbuf, n);
    // --- layer 2 ---
    agg_kernel<<<aggBlocks, TB, 0, stream>>>(hbuf, rowptr, csrc, cw, neigh, n);
    fc_kernel<128, 4, true><<<fc128Grid, TB, 0, stream>>>(neigh, W2, b2, hbuf, n);
    // --- classifier ---
    fc_kernel<32, 2, false><<<fc32Grid, TB, 0, stream>>>(hbuf, Wo, bo, out, n);
}

// Round 9
// 307.373 us; speedup vs baseline: 4.3569x; 1.0251x over previous
//
#include <hip/hip_runtime.h>

// ---------------------------------------------------------------------------
// WGraphSAGE: h' = relu(agg(h) @ W.T + b) x2, then out = h @ Wo.T + bo
// agg(h)[n] = deg*sum_m[n]/((deg+1)*sum_w[n]) + h[n]/(deg+1)   (0 if deg==0)
// R2->R3: fc spill fix (unroll 2): 1339 -> 373.5 us.
// R3->R7: hierarchical scan + half-wave float4 agg: 373.5 -> 315 us.
// R7 finding: scatter_kernel 50us, WRITE_SIZE 68MB vs 5.1MB payload (13x
// write amplification: 2 scattered 4B stores/edge into separate arrays).
// R8 fix (container died; resubmitted): pack (src,w) into one int2 epack[]
// -> 1x 8B store/edge (halves dirty lines); agg meta loads become int4.
// ---------------------------------------------------------------------------

#define D 128  // feature dim (F_IN == H == 128)

__global__ void count_kernel(const int* __restrict__ dst, int* __restrict__ deg, int e) {
    int i = blockIdx.x * blockDim.x + threadIdx.x;
    if (i < e) atomicAdd(&deg[dst[i]], 1);
}

// --- hierarchical exclusive scan: deg[0..n) -> rowptr[0..n] ---
// phase 1: per-block (1024 elems) tree reduction -> bsum[b]
__global__ void scan_blocksum(const int* __restrict__ deg, int* __restrict__ bsum, int n) {
    __shared__ int red[1024];
    const int t = threadIdx.x;
    const int i = blockIdx.x * 1024 + t;
    red[t] = (i < n) ? deg[i] : 0;
    __syncthreads();
    for (int off = 512; off > 0; off >>= 1) {
        if (t < off) red[t] += red[t + off];
        __syncthreads();
    }
    if (t == 0) bsum[blockIdx.x] = red[0];
}

// phase 2: one wave scans nb (<=64) block sums -> exclusive bbase[b]
__global__ void scan_bsum(const int* __restrict__ bsum, int* __restrict__ bbase, int nb) {
    const int l = threadIdx.x;
    int s = (l < nb) ? bsum[l] : 0;
    int v = s;
    for (int off = 1; off < 64; off <<= 1) {
        int u = __shfl_up(v, off, 64);
        if (l >= off) v += u;
    }
    if (l < nb) bbase[l] = v - s;  // exclusive prefix
}

// phase 3: per-block Hillis-Steele scan + bbase -> rowptr (+rowptr[n])
__global__ void scan_write(const int* __restrict__ deg, const int* __restrict__ bbase,
                           int* __restrict__ rowptr, int n) {
    __shared__ int part[1024];
    const int t = threadIdx.x;
    const int i = blockIdx.x * 1024 + t;
    const int v = (i < n) ? deg[i] : 0;
    part[t] = v;
    __syncthreads();
    for (int off = 1; off < 1024; off <<= 1) {
        int u = (t >= off) ? part[t - off] : 0;
        __syncthreads();
        part[t] += u;
        __syncthreads();
    }
    const int incl = part[t];
    const int base = bbase[blockIdx.x];
    if (i < n) rowptr[i] = base + incl - v;  // exclusive
    if (i == n - 1) rowptr[n] = base + incl;
}

// packed (src, w-bits) per edge: ONE 8B scattered store (was 2x 4B far apart)
__global__ void scatter_kernel(const int* __restrict__ src, const int* __restrict__ dst,
                               const float* __restrict__ w, const int* __restrict__ rowptr,
                               int* __restrict__ cur, int2* __restrict__ epack, int e) {
    int i = blockIdx.x * blockDim.x + threadIdx.x;
    if (i < e) {
        const int s = src[i];
        const int wb = __float_as_int(w[i]);
        const int d = dst[i];
        int pos = rowptr[d] + atomicAdd(&cur[d], 1);
        epack[pos] = make_int2(s, wb);
    }
}

// one wave per node; half-wave float4: lane l -> half=l>>5, q=l&31 owns dims
// 4q..4q+3 of edges with slot parity == half. 2 edges per gather instruction;
// metadata: one int4 load covers 2 edges (epack pairs, 16B-aligned via peel).
__global__ __launch_bounds__(256) void agg_kernel(
        const float* __restrict__ h, const int* __restrict__ rowptr,
        const int2* __restrict__ epack, float* __restrict__ neigh, int n) {
    const int wid  = (blockIdx.x * blockDim.x + threadIdx.x) >> 6;
    const int lane = threadIdx.x & 63;
    if (wid >= n) return;
    const int half = lane >> 5;
    const int q4   = (lane & 31) << 2;
    const int beg = rowptr[wid], end = rowptr[wid + 1];
    float4 aA = {0.f, 0.f, 0.f, 0.f}, aB = {0.f, 0.f, 0.f, 0.f};
    float ws = 0.f;
    int e = beg;
    // solo edge (peel to even index so int4 pair loads are 16B aligned):
    // all lanes gather the same row (dedup'd in cache); half 1 weights = 0.
    if ((e & 1) && e < end) {
        const int2 m = epack[e];
        const float w0 = half ? 0.f : __int_as_float(m.y);
        const float4 v = *(const float4*)(h + (size_t)m.x * D + q4);
        aA.x = fmaf(v.x, w0, aA.x); aA.y = fmaf(v.y, w0, aA.y);
        aA.z = fmaf(v.z, w0, aA.z); aA.w = fmaf(v.w, w0, aA.w);
        ws += w0; ++e;
    }
    for (; e + 3 < end; e += 4) {  // 4 edges = 2 int4 meta loads + 2 pair-gathers
        const int4 mA = *(const int4*)(epack + e);
        const int4 mB = *(const int4*)(epack + e + 2);
        const int   iA = half ? mA.z : mA.x,  iB = half ? mB.z : mB.x;
        const float fA = __int_as_float(half ? mA.w : mA.y);
        const float fB = __int_as_float(half ? mB.w : mB.y);
        const float4 vA = *(const float4*)(h + (size_t)iA * D + q4);
        const float4 vB = *(const float4*)(h + (size_t)iB * D + q4);
        aA.x = fmaf(vA.x, fA, aA.x); aA.y = fmaf(vA.y, fA, aA.y);
        aA.z = fmaf(vA.z, fA, aA.z); aA.w = fmaf(vA.w, fA, aA.w);
        aB.x = fmaf(vB.x, fB, aB.x); aB.y = fmaf(vB.y, fB, aB.y);
        aB.z = fmaf(vB.z, fB, aB.z); aB.w = fmaf(vB.w, fB, aB.w);
        ws += fA + fB;
    }
    if (e + 1 < end) {  // one remaining pair
        const int4 mA = *(const int4*)(epack + e);
        const int   iA = half ? mA.z : mA.x;
        const float fA = __int_as_float(half ? mA.w : mA.y);
        const float4 vA = *(const float4*)(h + (size_t)iA * D + q4);
        aA.x = fmaf(vA.x, fA, aA.x); aA.y = fmaf(vA.y, fA, aA.y);
        aA.z = fmaf(vA.z, fA, aA.z); aA.w = fmaf(vA.w, fA, aA.w);
        ws += fA; e += 2;
    }
    if (e < end) {  // solo tail
        const int2 m = epack[e];
        const float w0 = half ? 0.f : __int_as_float(m.y);
        const float4 v = *(const float4*)(h + (size_t)m.x * D + q4);
        aA.x = fmaf(v.x, w0, aA.x); aA.y = fmaf(v.y, w0, aA.y);
        aA.z = fmaf(v.z, w0, aA.z); aA.w = fmaf(v.w, w0, aA.w);
        ws += w0;
    }
    aA.x += aB.x; aA.y += aB.y; aA.z += aB.z; aA.w += aB.w;
    // cross-half combine: both halves hold same dims, different edge parity
    aA.x += __shfl_xor(aA.x, 32); aA.y += __shfl_xor(aA.y, 32);
    aA.z += __shfl_xor(aA.z, 32); aA.w += __shfl_xor(aA.w, 32);
    ws   += __shfl_xor(ws, 32);
    if (!half) {  // lanes 0-31 write the 512B row
        float4 o = {0.f, 0.f, 0.f, 0.f};
        if (end > beg) {
            const float deg  = (float)(end - beg);
            const float sw   = (ws == 0.f) ? 1.f : ws;
            const float invm = deg / ((deg + 1.f) * sw);
            const float invd = 1.f / (deg + 1.f);
            const float4 hc = *(const float4*)(h + (size_t)wid * D + q4);
            o.x = fmaf(aA.x, invm, hc.x * invd);
            o.y = fmaf(aA.y, invm, hc.y * invd);
            o.z = fmaf(aA.z, invm, hc.z * invd);
            o.w = fmaf(aA.w, invm, hc.w * invd);
        }
        *(float4*)(neigh + (size_t)wid * D + q4) = o;
    }
}

// Y[n][j] = (relu)( sum_k X[n][k] * W[j][k] + B[j] ), K = 128
// LDS: sWt[k][j] transposed-W; j-fast staging -> bank = j%32, conflict-free
// writes, no padding needed (reads are within-row / broadcast, pad-invariant).
// fc<128,4>: 64KB + 16KB = 80KB -> 2 blocks/CU. TM nodes x 4 outs per thread.
// k-loop: #pragma unroll 2 — full unroll spilled (R2: VGPR=256, 740MB scratch).
template <int OUT, int TM, bool RELU>
__global__ __launch_bounds__(256) void fc_kernel(
        const float* __restrict__ X, const float* __restrict__ W,
        const float* __restrict__ B, float* __restrict__ Y, int n) {
    constexpr int TNX = OUT / 4;    // threads along output dim
    constexpr int TY  = 256 / TNX;  // thread rows
    constexpr int NT  = TY * TM;    // node tile
    __shared__ float sWt[D][OUT];
    __shared__ float sN[NT][D];
    const int t = threadIdx.x;
    // stage W transposed, j-fast: lane writes column j=t%OUT -> bank j%32
    for (int p = t; p < OUT * (D / 4); p += 256) {
        int j = p % OUT, k4 = (p / OUT) << 2;
        const float4 v = *(const float4*)(W + j * D + k4);
        sWt[k4 + 0][j] = v.x; sWt[k4 + 1][j] = v.y;
        sWt[k4 + 2][j] = v.z; sWt[k4 + 3][j] = v.w;
    }
    const int tx = t % TNX, ty = t / TNX;
    const float4 bv = *(const float4*)(B + tx * 4);
    const int ntiles = (n + NT - 1) / NT;
    for (int tile = blockIdx.x; tile < ntiles; tile += gridDim.x) {
        const int node0 = tile * NT;
        __syncthreads();  // W ready (first iter) / prev compute done (later)
        for (int p = t; p < NT * (D / 4); p += 256) {
            int r = p >> 5, c = (p & 31) << 2;
            int nd = node0 + r;
            float4 v = make_float4(0.f, 0.f, 0.f, 0.f);
            if (nd < n) v = *(const float4*)(X + (size_t)nd * D + c);
            *(float4*)&sN[r][c] = v;
        }
        __syncthreads();
        float acc[TM][4];
        #pragma unroll
        for (int m = 0; m < TM; ++m)
            acc[m][0] = acc[m][1] = acc[m][2] = acc[m][3] = 0.f;
        #pragma unroll 2
        for (int k = 0; k < D; k += 4) {
            float4 xv[TM];
            #pragma unroll
            for (int m = 0; m < TM; ++m) xv[m] = *(const float4*)&sN[ty * TM + m][k];
            #pragma unroll
            for (int i = 0; i < 4; ++i) {
                const float4 wv = *(const float4*)&sWt[k + i][tx * 4];
                #pragma unroll
                for (int m = 0; m < TM; ++m) {
                    const float x = (i == 0) ? xv[m].x : (i == 1) ? xv[m].y
                                  : (i == 2) ? xv[m].z : xv[m].w;
                    acc[m][0] = fmaf(x, wv.x, acc[m][0]);
                    acc[m][1] = fmaf(x, wv.y, acc[m][1]);
                    acc[m][2] = fmaf(x, wv.z, acc[m][2]);
                    acc[m][3] = fmaf(x, wv.w, acc[m][3]);
                }
            }
        }
        #pragma unroll
        for (int m = 0; m < TM; ++m) {
            const int nd = node0 + ty * TM + m;
            if (nd < n) {
                float4 o;
                o.x = acc[m][0] + bv.x; o.y = acc[m][1] + bv.y;
                o.z = acc[m][2] + bv.z; o.w = acc[m][3] + bv.w;
                if (RELU) {
                    o.x = fmaxf(o.x, 0.f); o.y = fmaxf(o.y, 0.f);
                    o.z = fmaxf(o.z, 0.f); o.w = fmaxf(o.w, 0.f);
                }
                *(float4*)(Y + (size_t)nd * OUT + tx * 4) = o;
            }
        }
    }
}

extern "C" void kernel_launch(void* const* d_in, const int* in_sizes, int n_in,
                              void* d_out, int out_size, void* d_ws, size_t ws_size,
                              hipStream_t stream) {
    const float* feat = (const float*)d_in[0];
    const int*   src  = (const int*)d_in[1];
    const int*   dst  = (const int*)d_in[2];
    const float* w    = (const float*)d_in[3];
    const float* W1   = (const float*)d_in[4];
    const float* b1   = (const float*)d_in[5];
    const float* W2   = (const float*)d_in[6];
    const float* b2   = (const float*)d_in[7];
    const float* Wo   = (const float*)d_in[8];
    const float* bo   = (const float*)d_in[9];
    float* out = (float*)d_out;

    const int n = in_sizes[0] / D;   // 40000
    const int e = in_sizes[1];       // 640000

    // workspace carve-out (256B aligned slices)
    char* ws = (char*)d_ws;
    size_t off = 0;
    auto carve = [&](size_t bytes) {
        char* p = ws + off;
        off = (off + bytes + 255) & ~(size_t)255;
        return p;
    };
    int*   deg    = (int*)carve((size_t)n * 4);
    int*   cur    = (int*)carve((size_t)n * 4);
    int*   rowptr = (int*)carve((size_t)(n + 1) * 4);
    int2*  epack  = (int2*)carve((size_t)e * 8);
    float* neigh  = (float*)carve((size_t)n * D * 4);
    float* hbuf   = (float*)carve((size_t)n * D * 4);
    const int nScanBlk = (n + 1023) / 1024;          // 40
    int* bsum  = (int*)carve((size_t)nScanBlk * 4);
    int* bbase = (int*)carve((size_t)nScanBlk * 4);

    const int TB = 256;
    // --- CSR build (per launch; ws is re-poisoned by the harness) ---
    // one memset spans deg..cur (adjacent carves; pad bytes don't matter)
    hipMemsetAsync(deg, 0, (size_t)((char*)(cur + n) - (char*)deg), stream);
    count_kernel<<<(e + TB - 1) / TB, TB, 0, stream>>>(dst, deg, e);
    scan_blocksum<<<nScanBlk, 1024, 0, stream>>>(deg, bsum, n);
    scan_bsum<<<1, 64, 0, stream>>>(bsum, bbase, nScanBlk);
    scan_write<<<nScanBlk, 1024, 0, stream>>>(deg, bbase, rowptr, n);
    scatter_kernel<<<(e + TB - 1) / TB, TB, 0, stream>>>(src, dst, w, rowptr, cur, epack, e);

    const int aggBlocks = (n + 3) / 4;  // 4 nodes (waves) per 256-thread block
    const int fc128Grid = 512;          // 2 resident blocks/CU, grid-stride tiles
    const int fc32Grid  = (n + 63) / 64;

    // --- layer 1 ---
    agg_kernel<<<aggBlocks, TB, 0, stream>>>(feat, rowptr, epack, neigh, n);
    fc_kernel<128, 4, true><<<fc128Grid, TB, 0, stream>>>(neigh, W1, b1, hbuf, n);
    // --- layer 2 ---
    agg_kernel<<<aggBlocks, TB, 0, stream>>>(hbuf, rowptr, epack, neigh, n);
    fc_kernel<128, 4, true><<<fc128Grid, TB, 0, stream>>>(neigh, W2, b2, hbuf, n);
    // --- classifier ---
    fc_kernel<32, 2, false><<<fc32Grid, TB, 0, stream>>>(hbuf, Wo, bo, out, n);
}